// Round 8
// baseline (530.355 us; speedup 1.0000x reference)
//
#include <hip/hip_runtime.h>

#define KNN 16
static constexpr int BB = 16;
static constexpr float LEAK = 0.2f;
static constexpr float EPSV = 1e-5f;
typedef unsigned long long u64;

// ---------------- branch-free bitonic top-16 primitives -------------------
__device__ __forceinline__ void ce_asc(u64 &a, u64 &b) {
  u64 x = a, y = b; bool sw = y < x; a = sw ? y : x; b = sw ? x : y;
}
__device__ __forceinline__ void ce_desc(u64 &a, u64 &b) {
  u64 x = a, y = b; bool sw = x < y; a = sw ? y : x; b = sw ? x : y;
}
__device__ __forceinline__ void bitonic_sort16(u64 *T) {
#pragma unroll
  for (int k = 2; k <= 16; k <<= 1) {
#pragma unroll
    for (int j = k >> 1; j > 0; j >>= 1) {
#pragma unroll
      for (int i = 0; i < 16; ++i) {
        int l = i ^ j;
        if (l > i) {
          if ((i & k) == 0) ce_asc(T[i], T[l]); else ce_desc(T[i], T[l]);
        }
      }
    }
  }
}
// R asc, T asc -> R = 16 smallest of union, sorted asc
__device__ __forceinline__ void merge_sorted16(u64 *R, const u64 *T) {
#pragma unroll
  for (int i = 0; i < 16; ++i) {
    u64 t = T[15 - i];
    R[i] = t < R[i] ? t : R[i];
  }
#pragma unroll
  for (int j = 8; j > 0; j >>= 1) {
#pragma unroll
    for (int i = 0; i < 16; ++i) {
      int l = i ^ j;
      if (l > i) ce_asc(R[i], R[l]);
    }
  }
}

template<int KC>
__device__ __forceinline__ void merge_row(const u64* __restrict__ p, u64* R) {
#pragma unroll
  for (int s = 0; s < 16; ++s) R[s] = p[s];
#pragma unroll
  for (int c = 1; c < KC; ++c) {
    u64 T[16];
#pragma unroll
    for (int s = 0; s < 16; ++s) T[s] = p[(size_t)c*KNN + s];
    merge_sorted16(R, T);
  }
}

// ---------------- device: f0 = w_in @ coor + b_in (+ inv1 init) -----------
__device__ __forceinline__ void f0_dev(const float* __restrict__ x,
    const float* __restrict__ w_in, const float* __restrict__ b_in,
    float* __restrict__ f0, int* __restrict__ inv1, int bid) {
  int i = bid * 256 + threadIdx.x;
  inv1[i] = -1;
  float px = x[i*3+0], py = x[i*3+1], pz = x[i*3+2];
#pragma unroll
  for (int o = 0; o < 8; ++o) {
    f0[i*8+o] = w_in[o*3+0]*px + w_in[o*3+1]*py + w_in[o*3+2]*pz + b_in[o];
  }
}

// ---------------- device: kNN split-K partial top-16 ----------------------
__device__ void knn_part_dev(const float* __restrict__ qxyz, int Nq,
    const float* __restrict__ kxyz, int Nk, int KC, u64* __restrict__ part,
    int bid) {
  __shared__ float4 keys[1024];
  int nqb = (Nq + 255) >> 8;
  int c  = bid % KC;
  int qb = (bid / KC) % nqb;
  int b  = bid / (KC * nqb);
  int nkc = Nk / KC;
  int kbase = c * nkc;
  for (int j = threadIdx.x; j < nkc; j += 256) {
    const float* kp = kxyz + (size_t)(b*Nk + kbase + j)*3;
    float kx = kp[0], ky = kp[1], kz = kp[2];
    keys[j] = make_float4(kx, ky, kz, kx*kx + ky*ky + kz*kz);
  }
  __syncthreads();
  int q = (qb << 8) + threadIdx.x;
  if (q >= Nq) return;
  const float* qp = qxyz + (size_t)(b*Nq + q)*3;
  float qx = qp[0], qy = qp[1], qz = qp[2];
  float q2 = qx*qx + qy*qy + qz*qz;
  u64 R[16];
#pragma unroll
  for (int s = 0; s < 16; ++s) R[s] = 0xFFFFFFFFFFFFFFFFull;
  for (int j0 = 0; j0 < nkc; j0 += 16) {
    u64 T[16];
#pragma unroll
    for (int u = 0; u < 16; ++u) {
      float4 kk = keys[j0 + u];
      float qk = qx*kk.x + qy*kk.y + qz*kk.z;
      float d2 = q2 + kk.w - 2.0f*qk;
      int bb = __float_as_int(d2);
      unsigned k32 = (unsigned)bb ^ (unsigned)((bb >> 31) | 0x80000000);
      T[u] = ((u64)k32 << 32) | (unsigned)(kbase + j0 + u);
    }
    bitonic_sort16(T);
    merge_sorted16(R, T);
  }
  u64* op = part + ((size_t)(b*Nq + q)*KC + c)*KNN;
#pragma unroll
  for (int s = 0; s < KNN; ++s) op[s] = R[s];
}

// ---------------- device: segmented FPS (float4 LDS, tree argmax, DPP) ----
__device__ __forceinline__ u64 fps_max64(u64 a, u64 b) { return a > b ? a : b; }
template<int CTRL>
__device__ __forceinline__ u64 fps_dpp_u64(u64 v) {
  unsigned lo = (unsigned)__builtin_amdgcn_update_dpp(0, (int)(unsigned)(v & 0xFFFFFFFFull),
                                                      CTRL, 0xF, 0xF, false);
  unsigned hi = (unsigned)__builtin_amdgcn_update_dpp(0, (int)(unsigned)(v >> 32),
                                                      CTRL, 0xF, 0xF, false);
  return ((u64)hi << 32) | lo;
}
// SAVE=true: checkpoint state. SAVE=false (final segment): build inv + cq.
template<int P, bool SAVE>
__device__ void fps_seg_dev(const float* __restrict__ xyz, int np,
    int t0, int t1, int* __restrict__ fidx,
    float* __restrict__ g_dl, int* __restrict__ g_far,
    int* __restrict__ inv, float* __restrict__ cq, int b) {
  constexpr int NN = P * 256;
  __shared__ float4 sc[NN];
  __shared__ int s_fid[512];
  __shared__ u64 s_key[2][4];
  int tid = threadIdx.x;
  float px[P], py[P], pz[P], dl[P];
#pragma unroll
  for (int i = 0; i < P; ++i) {
    int p = tid + (i << 8);
    const float* pp = xyz + (size_t)(b*NN + p)*3;
    px[i] = pp[0]; py[i] = pp[1]; pz[i] = pp[2];
    sc[p] = make_float4(px[i], py[i], pz[i], 0.f);
  }
  int far;
  if (t0 == 0) {
#pragma unroll
    for (int i = 0; i < P; ++i) dl[i] = 1e10f;
    far = 0;
  } else {
#pragma unroll
    for (int i = 0; i < P; ++i) dl[i] = g_dl[b*NN + tid + (i << 8)];
    far = g_far[b];
  }
  __syncthreads();
  for (int t = t0; t < t1; ++t) {
    if (tid == 0) { fidx[b*np + t] = far; s_fid[t] = far; }
    float4 cc = sc[far];                      // single b128 broadcast
    // exact-arith dist update (matches reference elementwise order)
#pragma unroll
    for (int i = 0; i < P; ++i) {
      float dx = __fsub_rn(px[i], cc.x);
      float dy = __fsub_rn(py[i], cc.y);
      float dz = __fsub_rn(pz[i], cc.z);
      float d = __fadd_rn(__fadd_rn(__fmul_rn(dx,dx), __fmul_rn(dy,dy)), __fmul_rn(dz,dz));
      dl[i] = fminf(dl[i], d);
    }
    // tree max + mask/ctz index recovery (lowest slot on ties)
    float maxv;
    if constexpr (P == 8) {
      float m01 = fmaxf(dl[0], dl[1]), m23 = fmaxf(dl[2], dl[3]);
      float m45 = fmaxf(dl[4], dl[5]), m67 = fmaxf(dl[6], dl[7]);
      maxv = fmaxf(fmaxf(m01, m23), fmaxf(m45, m67));
    } else {
      maxv = dl[0];
#pragma unroll
      for (int i = 1; i < P; ++i) maxv = fmaxf(maxv, dl[i]);
    }
    unsigned msk = 0u;
#pragma unroll
    for (int i = 0; i < P; ++i) msk |= (dl[i] == maxv) ? (1u << i) : 0u;
    int ib = __builtin_ctz(msk);
    int bi = tid + (ib << 8);
    u64 k = ((u64)__float_as_uint(maxv) << 32) | (unsigned)(~bi);
    k = fps_max64(k, fps_dpp_u64<0x111>(k));  // row_shr:1
    k = fps_max64(k, fps_dpp_u64<0x112>(k));  // row_shr:2
    k = fps_max64(k, fps_dpp_u64<0x114>(k));  // row_shr:4
    k = fps_max64(k, fps_dpp_u64<0x118>(k));  // row_shr:8
    k = fps_max64(k, fps_dpp_u64<0x142>(k));  // row_bcast:15
    k = fps_max64(k, fps_dpp_u64<0x143>(k));  // row_bcast:31
    unsigned wlo = (unsigned)__builtin_amdgcn_readlane((int)(unsigned)(k & 0xFFFFFFFFull), 63);
    unsigned whi = (unsigned)__builtin_amdgcn_readlane((int)(unsigned)(k >> 32), 63);
    int buf = t & 1;
    if ((tid & 63) == 0)
      s_key[buf][tid >> 6] = ((u64)whi << 32) | wlo;
    __syncthreads();
    u64 best = s_key[buf][0];
    best = fps_max64(best, s_key[buf][1]);
    best = fps_max64(best, s_key[buf][2]);
    best = fps_max64(best, s_key[buf][3]);
    far = (int)(~(unsigned)(best & 0xFFFFFFFFull));
  }
  if constexpr (SAVE) {
#pragma unroll
    for (int i = 0; i < P; ++i) g_dl[b*NN + tid + (i << 8)] = dl[i];
    if (tid == 0) g_far[b] = far;
  } else {
    __syncthreads();
    for (int j = tid; j < np; j += 256) {
      int p = (j >= t0) ? s_fid[j] : fidx[b*np + j];
      inv[b*NN + p] = j;
      float4 c = sc[p];
      float* cp = cq + (size_t)(b*np + j)*3;
      cp[0] = c.x; cp[1] = c.y; cp[2] = c.z;
    }
  }
}

// ---------------- device: conv + fused GN stats + minmax over k ----------
template<int C, int O, int QB, int KC, int NB>
__device__ void conv_dev(const float* __restrict__ fsrc, int Nsrc,
    const float* __restrict__ fq, int Nq, const u64* __restrict__ part,
    const float* __restrict__ w, float* __restrict__ ym, float* __restrict__ yn,
    double2* __restrict__ pp1, int bid) {
  constexpr int Og = O / 4;
  constexpr int C4 = C / 4;
  __shared__ float ft[QB][KNN][C];
  __shared__ float fqs[QB][C];
  __shared__ int s_idx[QB][KNN];
  __shared__ double rs[256], rs2[256];
  int tid = threadIdx.x;
  int chunk = bid % NB;
  int b = bid / NB;
  int q0 = chunk * QB;
  if (tid < QB) {
    const u64* p = part + (size_t)(b*Nq + q0 + tid)*KC*KNN;
    u64 R[16];
    merge_row<KC>(p, R);
#pragma unroll
    for (int s = 0; s < 16; ++s) s_idx[tid][s] = (int)(unsigned)(R[s] & 0xFFFFFFFFu);
  } else if (tid >= 64 && tid < 64 + QB*C4) {
    int t = tid - 64;
    int ql = t / C4, c4 = t % C4;
    ((float4*)&fqs[ql][0])[c4] = ((const float4*)(fq + (size_t)(b*Nq + q0 + ql)*C))[c4];
  }
  __syncthreads();
  for (int v = tid; v < QB*KNN*C4; v += 256) {
    int row = v / C4, c4 = v % C4;
    int ql = row / KNN, k = row % KNN;
    int src = s_idx[ql][k];
    ((float4*)&ft[ql][k][0])[c4] = ((const float4*)(fsrc + (size_t)(b*Nsrc + src)*C))[c4];
  }
  __syncthreads();
  int ql = tid / O, o = tid % O;
  float4 wr4[C4];
  float bs = 0.f;
  const float4* wp4 = (const float4*)(w + (size_t)o*2*C);
#pragma unroll
  for (int c4 = 0; c4 < C4; ++c4) {
    float4 lo = wp4[c4], hi = wp4[C4 + c4];
    float4 fv = ((const float4*)&fqs[ql][0])[c4];
    bs += (hi.x - lo.x) * fv.x;
    bs += (hi.y - lo.y) * fv.y;
    bs += (hi.z - lo.z) * fv.z;
    bs += (hi.w - lo.w) * fv.w;
    wr4[c4] = lo;
  }
  float mx = -3.4e38f, mn = 3.4e38f;
  double s = 0.0, s2 = 0.0;
  for (int k = 0; k < KNN; ++k) {
    float acc = bs;
    const float4* fv = (const float4*)&ft[ql][k][0];
#pragma unroll
    for (int c4 = 0; c4 < C4; ++c4) {
      float4 v = fv[c4];
      acc += wr4[c4].x*v.x; acc += wr4[c4].y*v.y;
      acc += wr4[c4].z*v.z; acc += wr4[c4].w*v.w;
    }
    mx = fmaxf(mx, acc);
    mn = fminf(mn, acc);
    s += acc;
    s2 += (double)acc * (double)acc;
  }
  size_t oidx = (size_t)(b*Nq + q0 + ql)*O + o;
  ym[oidx] = mx;
  yn[oidx] = mn;
  rs[tid] = s; rs2[tid] = s2;
  __syncthreads();
#pragma unroll
  for (int st = QB/2; st > 0; st >>= 1) {
    if (ql < st) { rs[tid] += rs[tid + st*O]; rs2[tid] += rs2[tid + st*O]; }
    __syncthreads();
  }
#pragma unroll
  for (int st = Og/2; st > 0; st >>= 1) {
    if (tid < O && (o % Og) < st) { rs[tid] += rs[tid + st]; rs2[tid] += rs2[tid + st]; }
    __syncthreads();
  }
  if (tid < O && (o % Og) == 0) {
    int g = o / Og;
    pp1[((size_t)b*NB + chunk)*4 + g] = make_double2(rs[tid], rs2[tid]);
  }
}

// ---------------- device: finalize (+optional direct fq gather) -----------
template<int O, int NB, int FCH, int NQ, int NSEL>
__device__ void fin_dev(const float* __restrict__ ym, const float* __restrict__ yn,
    const double2* __restrict__ pp1, const float* __restrict__ gamma,
    const float* __restrict__ beta, float* __restrict__ fout,
    const int* __restrict__ inv, float* __restrict__ fqout, int bid) {
  constexpr int Og = O / 4;
  __shared__ double red[64], red2[64];
  __shared__ float s_mu[4], s_rsv[4];
  int tid = threadIdx.x;
  int b = bid / FCH;
  int f = bid % FCH;
  if (tid < 64) {
    int g = tid >> 4, j = tid & 15;
    double s = 0.0, s2 = 0.0;
    for (int c = j; c < NB; c += 16) {
      double2 v = pp1[((size_t)b*NB + c)*4 + g];
      s += v.x; s2 += v.y;
    }
    red[tid] = s; red2[tid] = s2;
  }
  __syncthreads();
#pragma unroll
  for (int st = 8; st > 0; st >>= 1) {
    if (tid < 64 && (tid & 15) < st) { red[tid] += red[tid+st]; red2[tid] += red2[tid+st]; }
    __syncthreads();
  }
  if (tid < 4) {
    double cnt = (double)Og * (double)NQ * (double)KNN;
    double mu = red[tid*16] / cnt;
    double var = red2[tid*16] / cnt - mu*mu;
    s_mu[tid] = (float)mu;
    s_rsv[tid] = 1.0f / sqrtf((float)var + EPSV);
  }
  __syncthreads();
  constexpr int PER = NQ * O / FCH;
  int e0 = f * PER;
  for (int e = e0 + tid; e < e0 + PER; e += 256) {
    int q = e / O, o = e % O;
    int g = o / Og;
    size_t idx = (size_t)(b*NQ + q)*O + o;
    float ga = gamma[o], be = beta[o];
    float ysel = (ga >= 0.f) ? ym[idx] : yn[idx];
    float xn = (ysel - s_mu[g]) * s_rsv[g];
    float yv = xn*ga + be;
    yv = yv > 0.f ? yv : LEAK*yv;
    fout[idx] = yv;
    if constexpr (NSEL > 0) {
      int j = inv[b*NQ + q];
      if (j >= 0) fqout[(size_t)(b*NSEL + j)*O + o] = yv;
    }
  }
}

// ---------------- dispatch wrappers ---------------------------------------
__global__ __launch_bounds__(256) void fusedA_kernel(const float* __restrict__ x,
    const float* __restrict__ w_in, const float* __restrict__ b_in,
    float* __restrict__ f0, u64* __restrict__ part, int* __restrict__ fidx1,
    float* __restrict__ g_dl, int* __restrict__ g_far, int* __restrict__ inv1) {
  int bid = blockIdx.x;
  if (bid < 16)       fps_seg_dev<8,true>(x, 512, 0, 256, fidx1, g_dl, g_far, nullptr, nullptr, bid);
  else if (bid < 528) knn_part_dev(x, 2048, x, 2048, 4, part, bid - 16);
  else                f0_dev(x, w_in, b_in, f0, inv1, bid - 528);
}

__global__ __launch_bounds__(256) void conv1_kernel(const float* __restrict__ x,
    int* __restrict__ fidx1, float* __restrict__ g_dl, int* __restrict__ g_far,
    int* __restrict__ inv1, float* __restrict__ cq1,
    const float* __restrict__ f0, const u64* __restrict__ part,
    const float* __restrict__ w1, float* __restrict__ ym, float* __restrict__ yn,
    double2* __restrict__ pp1) {
  int bid = blockIdx.x;
  if (bid < 16) fps_seg_dev<8,false>(x, 512, 256, 512, fidx1, g_dl, g_far, inv1, cq1, bid);
  else          conv_dev<8,32,8,4,256>(f0, 2048, f0, 2048, part, w1, ym, yn, pp1, bid - 16);
}

__global__ __launch_bounds__(256) void fin1_kernel(const float* __restrict__ ym,
    const float* __restrict__ yn, const double2* __restrict__ pp1,
    const float* __restrict__ g1, const float* __restrict__ be1,
    float* __restrict__ f1, const int* __restrict__ inv1, float* __restrict__ fq1) {
  fin_dev<32,256,32,2048,512>(ym, yn, pp1, g1, be1, f1, inv1, fq1, blockIdx.x);
}

__global__ __launch_bounds__(256) void fusedB_kernel(const float* __restrict__ cq1,
    const float* __restrict__ x, u64* __restrict__ part2, u64* __restrict__ part3,
    int* __restrict__ fidx2, float* __restrict__ g_dl, int* __restrict__ g_far,
    int* __restrict__ inv2) {
  int bid = blockIdx.x;
  if (bid < 16) {
    fps_seg_dev<2,true>(cq1, 128, 0, 64, fidx2, g_dl, g_far, nullptr, nullptr, bid);
  } else if (bid < 272) {
    if (bid < 48) inv2[(bid - 16)*256 + threadIdx.x] = -1;   // 32*256 = 16*512
    knn_part_dev(cq1, 512, x, 2048, 8, part2, bid - 16);
  } else {
    knn_part_dev(cq1, 512, cq1, 512, 8, part3, bid - 272);
  }
}

__global__ __launch_bounds__(256) void conv2_kernel(const float* __restrict__ cq1,
    int* __restrict__ fidx2, float* __restrict__ g_dl, int* __restrict__ g_far,
    int* __restrict__ inv2, float* __restrict__ cq2,
    const float* __restrict__ f1, const float* __restrict__ fq1,
    const u64* __restrict__ part2, const float* __restrict__ w2,
    float* __restrict__ ym, float* __restrict__ yn, double2* __restrict__ pp1) {
  int bid = blockIdx.x;
  if (bid < 16) fps_seg_dev<2,false>(cq1, 128, 64, 128, fidx2, g_dl, g_far, inv2, cq2, bid);
  else          conv_dev<32,64,4,8,128>(f1, 2048, fq1, 512, part2, w2, ym, yn, pp1, bid - 16);
}

__global__ __launch_bounds__(256) void fin2_kernel(const float* __restrict__ ym,
    const float* __restrict__ yn, const double2* __restrict__ pp1,
    const float* __restrict__ g2, const float* __restrict__ be2,
    float* __restrict__ f2) {
  fin_dev<64,128,16,512,0>(ym, yn, pp1, g2, be2, f2, nullptr, nullptr, blockIdx.x);
}

__global__ __launch_bounds__(256) void conv3k4_kernel(const float* __restrict__ cq2,
    const float* __restrict__ cq1, u64* __restrict__ part4,
    const float* __restrict__ f2, const u64* __restrict__ part3,
    const float* __restrict__ w3, float* __restrict__ ym, float* __restrict__ yn,
    double2* __restrict__ pp1) {
  int bid = blockIdx.x;
  if (bid < 128) knn_part_dev(cq2, 128, cq1, 512, 8, part4, bid);
  else           conv_dev<64,64,4,8,128>(f2, 512, f2, 512, part3, w3, ym, yn, pp1, bid - 128);
}

__global__ __launch_bounds__(256) void fin3_kernel(const float* __restrict__ ym,
    const float* __restrict__ yn, const double2* __restrict__ pp1,
    const float* __restrict__ g3, const float* __restrict__ be3,
    float* __restrict__ f3, const int* __restrict__ inv2, float* __restrict__ fq2) {
  fin_dev<64,128,16,512,128>(ym, yn, pp1, g3, be3, f3, inv2, fq2, blockIdx.x);
}

__global__ __launch_bounds__(256) void conv4_kernel(const float* __restrict__ f3,
    const float* __restrict__ fq2, const u64* __restrict__ part4,
    const float* __restrict__ w4, float* __restrict__ ym, float* __restrict__ yn,
    double2* __restrict__ pp1) {
  conv_dev<64,128,2,8,64>(f3, 512, fq2, 128, part4, w4, ym, yn, pp1, blockIdx.x);
}

__global__ __launch_bounds__(256) void fin4_kernel(const float* __restrict__ ym,
    const float* __restrict__ yn, const double2* __restrict__ pp1,
    const float* __restrict__ g4, const float* __restrict__ be4,
    float* __restrict__ f4) {
  fin_dev<128,64,8,128,0>(ym, yn, pp1, g4, be4, f4, nullptr, nullptr, blockIdx.x);
}

extern "C" void kernel_launch(void* const* d_in, const int* in_sizes, int n_in,
                              void* d_out, int out_size, void* d_ws, size_t ws_size,
                              hipStream_t stream) {
  const float* x    = (const float*)d_in[0];
  const float* w_in = (const float*)d_in[3];
  const float* b_in = (const float*)d_in[4];
  const float* w1 = (const float*)d_in[5];
  const float* g1 = (const float*)d_in[6];
  const float* be1= (const float*)d_in[7];
  const float* w2 = (const float*)d_in[8];
  const float* g2 = (const float*)d_in[9];
  const float* be2= (const float*)d_in[10];
  const float* w3 = (const float*)d_in[11];
  const float* g3 = (const float*)d_in[12];
  const float* be3= (const float*)d_in[13];
  const float* w4 = (const float*)d_in[14];
  const float* g4 = (const float*)d_in[15];
  const float* be4= (const float*)d_in[16];
  float* out = (float*)d_out;
  (void)in_sizes; (void)n_in; (void)out_size; (void)ws_size;

  char* ws = (char*)d_ws;
  size_t off = 0;
  auto alloc = [&](size_t count) {        // count in 4-byte units
    void* p = ws + off;
    off += (count * 4 + 255) & ~(size_t)255;
    return p;
  };
  float* f0    = (float*)alloc(16*2048*8);
  float* f1    = (float*)alloc(16*2048*32);
  float* f2    = (float*)alloc(16*512*64);
  float* f3    = (float*)alloc(16*512*64);
  float* fq1   = (float*)alloc(16*512*32);
  float* fq2   = (float*)alloc(16*128*64);
  float* cq1   = (float*)alloc(16*512*3);
  float* ym    = (float*)alloc(16*2048*32);
  float* yn    = (float*)alloc(16*2048*32);
  double2* pp1 = (double2*)alloc(16*256*4*4);
  int* fidx1   = (int*)alloc(16*512);
  int* fidx2   = (int*)alloc(16*128);
  int* inv1    = (int*)alloc(16*2048);
  int* inv2    = (int*)alloc(16*512);
  float* g_dl1 = (float*)alloc(16*2048);
  int* g_far1  = (int*)alloc(16);
  float* g_dl2 = (float*)alloc(16*512);
  int* g_far2  = (int*)alloc(16);
  u64* part    = (u64*)alloc(2 * 16*2048*4*16);   // 16 MB (2M u64)
  u64* partB   = part + (size_t)16*512*8*16;      // second region for knn3

  float* cq2 = out;              // (16,128,3)
  float* f4  = out + 16*128*3;   // (16,128,128)

  // L1: knn1 + f0(+inv1 init) + fps1[0,256)
  fusedA_kernel<<<656, 256, 0, stream>>>(x, w_in, b_in, f0, part, fidx1, g_dl1, g_far1, inv1);
  // L1 conv + fps1[256,512) -> cq1, inv1
  conv1_kernel<<<4112, 256, 0, stream>>>(x, fidx1, g_dl1, g_far1, inv1, cq1, f0, part, w1, ym, yn, pp1);
  // L1 fin -> f1 (+fq1 via inv1)
  fin1_kernel<<<512, 256, 0, stream>>>(ym, yn, pp1, g1, be1, f1, inv1, fq1);

  // L2+L3 knn + inv2 init + fps2[0,64)
  fusedB_kernel<<<528, 256, 0, stream>>>(cq1, x, part, partB, fidx2, g_dl2, g_far2, inv2);
  // L2 conv + fps2[64,128) -> cq2(out), inv2
  conv2_kernel<<<2064, 256, 0, stream>>>(cq1, fidx2, g_dl2, g_far2, inv2, cq2, f1, fq1, part, w2, ym, yn, pp1);
  fin2_kernel<<<256, 256, 0, stream>>>(ym, yn, pp1, g2, be2, f2);

  // L3 conv + L4 knn (cq2 ready)
  conv3k4_kernel<<<2176, 256, 0, stream>>>(cq2, cq1, part, f2, partB, w3, ym, yn, pp1);
  // L3 fin -> f3 (+fq2 via inv2)
  fin3_kernel<<<256, 256, 0, stream>>>(ym, yn, pp1, g3, be3, f3, inv2, fq2);

  // L4
  conv4_kernel<<<1024, 256, 0, stream>>>(f3, fq2, part, w4, ym, yn, pp1);
  fin4_kernel<<<128, 256, 0, stream>>>(ym, yn, pp1, g4, be4, f4);
}